// Round 1
// 415.127 us; speedup vs baseline: 1.0034x; 1.0034x over previous
//
#include <hip/hip_runtime.h>

// out = softmax(x, axis=-1) * v
// x: [B,H,S,S] fp32, v: [B,H,1,S] fp32, out: [B,H,S,S] fp32; B=4 H=16 S=1024.
// One wave per 2 consecutive rows (rows 2w, 2w+1 share the same (b,h) and v
// slice). Each lane holds 16 floats per row in registers.
//
// Online-softmax restructure vs previous version: lane-local max, exp2 and
// partial sum are computed as loads return (hidden under HBM latency); a
// SINGLE combined (max,sum) butterfly replaces the separate max- and
// sum-butterflies, collapsing three serial phases into one. exp via
// exp2(fma(x, log2e, -m2)) saves one VALU op per element; 1/S via v_rcp_f32.

#define SEQ 1024
#define WAVES_PER_BLOCK 4
#define LOG2E 1.44269504088896340736f

// native clang vector type — required by __builtin_nontemporal_{load,store}
typedef float vf4 __attribute__((ext_vector_type(4)));

__global__ __launch_bounds__(256) void softmax_mul_kernel(
    const float* __restrict__ x,
    const float* __restrict__ v,
    float* __restrict__ out,
    int npairs) {
  const int wave = threadIdx.x >> 6;
  const int lane = threadIdx.x & 63;
  const int pair = blockIdx.x * WAVES_PER_BLOCK + wave;
  if (pair >= npairs) return;

  const size_t row0 = (size_t)pair * 2;              // even row
  const vf4* __restrict__ x4 = (const vf4*)(x + row0 * SEQ);
  vf4* __restrict__ o4 = (vf4*)(out + row0 * SEQ);
  const vf4* __restrict__ v4 = (const vf4*)(v + (row0 >> 10) * SEQ);

  // ---- issue all global traffic up front: 2 rows of x (nt) + v (cached)
  vf4 a[4], b[4], vv[4];
#pragma unroll
  for (int j = 0; j < 4; ++j) a[j] = __builtin_nontemporal_load(&x4[lane + 64 * j]);
#pragma unroll
  for (int j = 0; j < 4; ++j) b[j] = __builtin_nontemporal_load(&x4[256 + lane + 64 * j]);
#pragma unroll
  for (int j = 0; j < 4; ++j) vv[j] = v4[lane + 64 * j];

  // ---- lane-local maxima (raw domain), overlapped with load returns
  float ma = -INFINITY, mb = -INFINITY;
#pragma unroll
  for (int j = 0; j < 4; ++j) {
    ma = fmaxf(ma, fmaxf(fmaxf(a[j].x, a[j].y), fmaxf(a[j].z, a[j].w)));
    mb = fmaxf(mb, fmaxf(fmaxf(b[j].x, b[j].y), fmaxf(b[j].z, b[j].w)));
  }
  // base-2 domain lane maxima
  float m2a = ma * LOG2E;
  float m2b = mb * LOG2E;

  // ---- lane-local exp2 (in place) + lane-local partial sums
  float sa = 0.f, sb = 0.f;
#pragma unroll
  for (int j = 0; j < 4; ++j) {
    a[j].x = __builtin_amdgcn_exp2f(__builtin_fmaf(a[j].x, LOG2E, -m2a));
    a[j].y = __builtin_amdgcn_exp2f(__builtin_fmaf(a[j].y, LOG2E, -m2a));
    a[j].z = __builtin_amdgcn_exp2f(__builtin_fmaf(a[j].z, LOG2E, -m2a));
    a[j].w = __builtin_amdgcn_exp2f(__builtin_fmaf(a[j].w, LOG2E, -m2a));
    b[j].x = __builtin_amdgcn_exp2f(__builtin_fmaf(b[j].x, LOG2E, -m2b));
    b[j].y = __builtin_amdgcn_exp2f(__builtin_fmaf(b[j].y, LOG2E, -m2b));
    b[j].z = __builtin_amdgcn_exp2f(__builtin_fmaf(b[j].z, LOG2E, -m2b));
    b[j].w = __builtin_amdgcn_exp2f(__builtin_fmaf(b[j].w, LOG2E, -m2b));
    sa += (a[j].x + a[j].y) + (a[j].z + a[j].w);
    sb += (b[j].x + b[j].y) + (b[j].z + b[j].w);
  }

  // ---- single combined (max, sum) butterfly; two independent chains for ILP
  const float lm2a = m2a, lm2b = m2b;  // save lane-local maxima
#pragma unroll
  for (int off = 32; off > 0; off >>= 1) {
    const float oma = __shfl_xor(m2a, off, 64);
    const float osa = __shfl_xor(sa, off, 64);
    const float omb = __shfl_xor(m2b, off, 64);
    const float osb = __shfl_xor(sb, off, 64);
    const float nma = fmaxf(m2a, oma);
    const float nmb = fmaxf(m2b, omb);
    sa = sa * __builtin_amdgcn_exp2f(m2a - nma)
       + osa * __builtin_amdgcn_exp2f(oma - nma);
    sb = sb * __builtin_amdgcn_exp2f(m2b - nmb)
       + osb * __builtin_amdgcn_exp2f(omb - nmb);
    m2a = nma;
    m2b = nmb;
  }

  // per-row rescale factor: exp2(lane_max - global_max) / global_sum
  const float fa = __builtin_amdgcn_exp2f(lm2a - m2a) * __builtin_amdgcn_rcpf(sa);
  const float fb = __builtin_amdgcn_exp2f(lm2b - m2b) * __builtin_amdgcn_rcpf(sb);

  // ---- scale by v, nontemporal store
#pragma unroll
  for (int j = 0; j < 4; ++j) {
    vf4 fva, fvb, oa, ob;
    fva.x = fa * vv[j].x; fva.y = fa * vv[j].y;
    fva.z = fa * vv[j].z; fva.w = fa * vv[j].w;
    fvb.x = fb * vv[j].x; fvb.y = fb * vv[j].y;
    fvb.z = fb * vv[j].z; fvb.w = fb * vv[j].w;
    oa.x = a[j].x * fva.x; oa.y = a[j].y * fva.y;
    oa.z = a[j].z * fva.z; oa.w = a[j].w * fva.w;
    ob.x = b[j].x * fvb.x; ob.y = b[j].y * fvb.y;
    ob.z = b[j].z * fvb.z; ob.w = b[j].w * fvb.w;
    __builtin_nontemporal_store(oa, &o4[lane + 64 * j]);
    __builtin_nontemporal_store(ob, &o4[256 + lane + 64 * j]);
  }
}

extern "C" void kernel_launch(void* const* d_in, const int* in_sizes, int n_in,
                              void* d_out, int out_size, void* d_ws, size_t ws_size,
                              hipStream_t stream) {
  const float* x = (const float*)d_in[0];
  const float* v = (const float*)d_in[1];
  float* out = (float*)d_out;
  const int rows = in_sizes[0] / SEQ;       // B*H*S = 65536
  const int npairs = rows / 2;              // 32768 waves
  const int grid = (npairs + WAVES_PER_BLOCK - 1) / WAVES_PER_BLOCK;
  softmax_mul_kernel<<<grid, 256, 0, stream>>>(x, v, out, npairs);
}